// Round 17
// baseline (466.047 us; speedup 1.0000x reference)
//
#include <hip/hip_runtime.h>
#include <hip/hip_cooperative_groups.h>

namespace cg = cooperative_groups;

#define WAVE 64
#define BROWS 256        // rows per bucket (bucket = node >> 8)
#define SRCMASK 0x3FFFF  // 18-bit src field in packed entry
#define EPC 1024         // edges per build chunk (256 threads x 4)
#define ENTCAP 4096      // LDS entry cache per bucket in csr phase
#define GRID_BUILD 512   // cooperative grid (2 blocks/CU on 256 CUs)

// z stored BF16 row-major z[node][64] (128 B). Accumulation fp32 throughout.

__device__ __forceinline__ unsigned short f2bf(float f) {
    unsigned u = __float_as_uint(f);
    u += 0x7FFF + ((u >> 16) & 1);   // round-to-nearest-even
    return (unsigned short)(u >> 16);
}
__device__ __forceinline__ float bf2f(unsigned short v) {
    return __uint_as_float((unsigned)v << 16);
}
__device__ __forceinline__ void addbf8(float* a, uint4 v) {
    a[0] += __uint_as_float(v.x << 16);
    a[1] += __uint_as_float(v.x & 0xFFFF0000u);
    a[2] += __uint_as_float(v.y << 16);
    a[3] += __uint_as_float(v.y & 0xFFFF0000u);
    a[4] += __uint_as_float(v.z << 16);
    a[5] += __uint_as_float(v.z & 0xFFFF0000u);
    a[6] += __uint_as_float(v.w << 16);
    a[7] += __uint_as_float(v.w & 0xFFFF0000u);
}

// ================= fused cooperative CSR build =================
// P1 hist -> P2 per-bucket scan -> P3 total scan (+acc=x0 on idle blocks)
// -> P4 bin (LDS-staged) -> P5 CSR finalize + bf16 z0.
__global__ void k_build(const int* __restrict__ eu, const int* __restrict__ ei,
                        int nE, int nU, int nBkt, int nChunk,
                        int* __restrict__ cntBB, int* __restrict__ baseBB,
                        int* __restrict__ bktTot, int* __restrict__ bktBase,
                        int* __restrict__ bins, int* __restrict__ row_ptr,
                        int* __restrict__ col, unsigned short* __restrict__ z0,
                        const float* __restrict__ ue, const float* __restrict__ ie,
                        const int* __restrict__ users, const int* __restrict__ items,
                        int B, float* __restrict__ acc, int N, int total) {
    cg::grid_group grid = cg::this_grid();
    __shared__ __align__(16) char smem[30720];
    int t = threadIdx.x;

    // ---------- P1: per-chunk bucket histogram ----------
    {
        int* h4 = (int*)smem;                       // 4 * nBkt ints
        for (int c = blockIdx.x; c < nChunk; c += gridDim.x) {
            for (int i = t; i < 4 * nBkt; i += 256) h4[i] = 0;
            __syncthreads();
            int* hw = h4 + (t >> 6) * nBkt;
            if ((c + 1) * EPC <= nE) {
                int i4 = c * 256 + t;
                int4 u = ((const int4*)eu)[i4];
                int4 v = ((const int4*)ei)[i4];
                atomicAdd(&hw[u.x >> 8], 1); atomicAdd(&hw[(nU + v.x) >> 8], 1);
                atomicAdd(&hw[u.y >> 8], 1); atomicAdd(&hw[(nU + v.y) >> 8], 1);
                atomicAdd(&hw[u.z >> 8], 1); atomicAdd(&hw[(nU + v.z) >> 8], 1);
                atomicAdd(&hw[u.w >> 8], 1); atomicAdd(&hw[(nU + v.w) >> 8], 1);
            } else {
                for (int e = c * EPC + t; e < nE; e += 256) {
                    atomicAdd(&hw[eu[e] >> 8], 1);
                    atomicAdd(&hw[(nU + ei[e]) >> 8], 1);
                }
            }
            __syncthreads();
            int* dst = cntBB + (size_t)c * nBkt;
            for (int i = t; i < nBkt; i += 256)
                dst[i] = h4[i] + h4[nBkt + i] + h4[2 * nBkt + i] + h4[3 * nBkt + i];
            __syncthreads();
        }
    }
    grid.sync();

    // ---------- P2: per-bucket exclusive scan over chunks ----------
    {
        int* sp = (int*)smem;
        int C = (nChunk + 255) / 256;               // 3 for nChunk=586
        for (int b = blockIdx.x; b < nBkt; b += gridDim.x) {
            int vals[4];
            int sum = 0;
            for (int k = 0; k < 4; k++) {
                if (k >= C) break;
                int j = t * C + k;
                int v = (j < nChunk) ? cntBB[(size_t)j * nBkt + b] : 0;
                vals[k] = v; sum += v;
            }
            sp[t] = sum;
            __syncthreads();
            for (int o = 1; o < 256; o <<= 1) {
                int x = (t >= o) ? sp[t - o] : 0;
                __syncthreads();
                sp[t] += x;
                __syncthreads();
            }
            int run = sp[t] - sum;                  // exclusive
            for (int k = 0; k < 4; k++) {
                if (k >= C) break;
                int j = t * C + k;
                if (j < nChunk) { baseBB[(size_t)b * nChunk + j] = run; run += vals[k]; }
            }
            if (t == 0) bktTot[b] = sp[255];
            __syncthreads();
        }
    }
    grid.sync();

    // ---------- P3: bucket-total scan (block 0); others init acc = x0 ----------
    if (blockIdx.x == 0) {
        int* sp = (int*)smem;
        int C = (nBkt + 255) / 256;                 // 3
        int vals[4];
        int sum = 0;
        for (int k = 0; k < 4; k++) {
            if (k >= C) break;
            int i = t * C + k;
            int v = (i < nBkt) ? bktTot[i] : 0;
            vals[k] = v; sum += v;
        }
        sp[t] = sum;
        __syncthreads();
        for (int o = 1; o < 256; o <<= 1) {
            int x = (t >= o) ? sp[t - o] : 0;
            __syncthreads();
            sp[t] += x;
            __syncthreads();
        }
        int run = sp[t] - sum;
        for (int k = 0; k < 4; k++) {
            if (k >= C) break;
            int i = t * C + k;
            if (i < nBkt) { bktBase[i] = run; run += vals[k]; }
        }
        if (t == 0) { bktBase[nBkt] = total; row_ptr[N] = total; }
    } else {
        // acc[b] = x0[b] (exact fp32; covers deg==0 nodes)
        for (int idx = (blockIdx.x - 1) * 256 + t; idx < 2 * B * 16;
             idx += (gridDim.x - 1) * 256) {
            int b = idx >> 4, f4 = idx & 15;
            const float4* x0 = (b < B)
                ? ((const float4*)ue) + (size_t)users[b] * 16
                : ((const float4*)ie) + (size_t)items[b - B] * 16;
            ((float4*)acc)[(size_t)b * 16 + f4] = x0[f4];
        }
    }
    grid.sync();

    // ---------- P4: bin entries (LDS-staged sort by bucket) ----------
    {
        int* ent            = (int*)smem;                        // 2048 ints
        unsigned short* ebk = (unsigned short*)(smem + 8192);    // 2048 shorts
        int* h2             = (int*)(smem + 12288);              // 2*nBkt ints
        int* lcur           = (int*)(smem + 20480);              // nBkt ints
        int* dlt            = (int*)(smem + 24576);              // nBkt ints
        int* sp             = (int*)(smem + 28672);              // 256 ints
        for (int c = blockIdx.x; c < nChunk; c += gridDim.x) {
            if ((c + 1) * EPC <= nE) {
                for (int i = t; i < 2 * nBkt; i += 256) h2[i] = 0;
                __syncthreads();
                int myb[8], mye[8];
                {
                    int i4 = c * 256 + t;
                    int4 uu = ((const int4*)eu)[i4];
                    int4 vv = ((const int4*)ei)[i4];
                    #pragma unroll
                    for (int k = 0; k < 4; k++) {
                        int u  = (k == 0) ? uu.x : (k == 1) ? uu.y : (k == 2) ? uu.z : uu.w;
                        int i2 = (k == 0) ? vv.x : (k == 1) ? vv.y : (k == 2) ? vv.z : vv.w;
                        int v = nU + i2;
                        myb[2 * k]     = u >> 8; mye[2 * k]     = ((u & 255) << 18) | v;
                        myb[2 * k + 1] = v >> 8; mye[2 * k + 1] = ((v & 255) << 18) | u;
                    }
                }
                int* hs = h2 + (t >> 7) * nBkt;
                #pragma unroll
                for (int k = 0; k < 8; k++) atomicAdd(&hs[myb[k]], 1);
                __syncthreads();
                int C = (nBkt + 255) / 256;         // 3
                int vals[4];
                int sum = 0;
                for (int k = 0; k < 4; k++) {
                    if (k >= C) break;
                    int b = t * C + k;
                    int v = (b < nBkt) ? (h2[b] + h2[nBkt + b]) : 0;
                    vals[k] = v; sum += v;
                }
                sp[t] = sum;
                __syncthreads();
                for (int o = 1; o < 256; o <<= 1) {
                    int x = (t >= o) ? sp[t - o] : 0;
                    __syncthreads();
                    sp[t] += x;
                    __syncthreads();
                }
                int run = sp[t] - sum;
                for (int k = 0; k < 4; k++) {
                    if (k >= C) break;
                    int b = t * C + k;
                    if (b < nBkt) {
                        lcur[b] = run;
                        dlt[b] = bktBase[b] + baseBB[(size_t)b * nChunk + c] - run;
                        run += vals[k];
                    }
                }
                __syncthreads();
                #pragma unroll
                for (int k = 0; k < 8; k++) {
                    int p = atomicAdd(&lcur[myb[k]], 1);
                    ent[p] = mye[k];
                    ebk[p] = (unsigned short)myb[k];
                }
                __syncthreads();
                int n4 = sp[255];
                for (int i = t; i < n4; i += 256)
                    bins[dlt[ebk[i]] + i] = ent[i];
                __syncthreads();
            } else {
                // tail chunk: scattered path
                for (int i = t; i < nBkt; i += 256)
                    lcur[i] = bktBase[i] + baseBB[(size_t)i * nChunk + c];
                __syncthreads();
                for (int e = c * EPC + t; e < nE; e += 256) {
                    int u = eu[e];
                    int v = nU + ei[e];
                    int p1 = atomicAdd(&lcur[u >> 8], 1);
                    int p2 = atomicAdd(&lcur[v >> 8], 1);
                    bins[p1] = ((u & 255) << 18) | v;
                    bins[p2] = ((v & 255) << 18) | u;
                }
                __syncthreads();
            }
        }
    }
    grid.sync();

    // ---------- P5: per-bucket CSR finalize + fused bf16 z0 ----------
    {
        int* ent    = (int*)smem;                    // ENTCAP ints (16 KB)
        int* h4     = (int*)(smem + 16384);          // 4*BROWS
        int* cur4   = (int*)(smem + 20480);          // 4*BROWS
        int* sc     = (int*)(smem + 24576);          // BROWS
        float* sInv = (float*)(smem + 25600);        // BROWS
        int w = t >> 6;
        for (int b = blockIdx.x; b < nBkt; b += gridDim.x) {
            int base = bktBase[b];
            int n = bktBase[b + 1] - base;
            h4[t] = 0; h4[256 + t] = 0; h4[512 + t] = 0; h4[768 + t] = 0;
            __syncthreads();
            int* hw = h4 + w * BROWS;
            for (int i = t; i < n; i += 256) {
                int p = bins[base + i];
                if (i < ENTCAP) ent[i] = p;
                atomicAdd(&hw[p >> 18], 1);
            }
            __syncthreads();
            int v = h4[t] + h4[256 + t] + h4[512 + t] + h4[768 + t];
            sc[t] = v;
            __syncthreads();
            for (int o = 1; o < 256; o <<= 1) {
                int x = (t >= o) ? sc[t - o] : 0;
                __syncthreads();
                sc[t] += x;
                __syncthreads();
            }
            int excl = sc[t] - v;
            int row = b * BROWS + t;
            if (row < N) row_ptr[row] = base + excl;
            sInv[t] = (v > 0) ? (1.0f / sqrtf((float)v)) : 0.0f;
            cur4[t]       = excl;
            cur4[256 + t] = excl + h4[t];
            cur4[512 + t] = excl + h4[t] + h4[256 + t];
            cur4[768 + t] = excl + h4[t] + h4[256 + t] + h4[512 + t];
            __syncthreads();
            // fused z0 = inv .* x0 (bf16 RTNE)
            int rf = t & 15, rg = t >> 4;
            for (int pass = 0; pass < 16; pass++) {
                int r = pass * 16 + rg;
                int rr = b * BROWS + r;
                if (rr < N) {
                    const float4* src = (rr < nU)
                        ? ((const float4*)ue) + (size_t)rr * 16
                        : ((const float4*)ie) + (size_t)(rr - nU) * 16;
                    float4 val = src[rf];
                    float scl = sInv[r];
                    ushort4 o;
                    o.x = f2bf(val.x * scl);
                    o.y = f2bf(val.y * scl);
                    o.z = f2bf(val.z * scl);
                    o.w = f2bf(val.w * scl);
                    ((ushort4*)z0)[(size_t)rr * 16 + rf] = o;
                }
            }
            // placement with per-wave cursors (same i->thread mapping as hist)
            int* cw = cur4 + w * BROWS;
            for (int i = t; i < n; i += 256) {
                int p = (i < ENTCAP) ? ent[i] : bins[base + i];
                int pos = base + atomicAdd(&cw[p >> 18], 1);
                col[pos] = p & SRCMASK;
            }
            __syncthreads();
        }
    }
}

// ---------------- SPMM: masked 8-wide gather + optional batch tail ---------------
// mode==0: tail is a no-op (acc pre-initialized in build); mode==1: tail adds
// x_l = sqrt(deg)*z_in at batch rows.
__global__ void k_spmm(const int* __restrict__ row_ptr, const int* __restrict__ col,
                       const unsigned short* __restrict__ x,
                       unsigned short* __restrict__ y, int N, int nBlkMain,
                       const int* __restrict__ users, const int* __restrict__ items,
                       int B, int nU, float* __restrict__ acc, int mode) {
    int t = threadIdx.x;
    if ((int)blockIdx.x < nBlkMain) {
        int grp = t >> 3, f = t & 7;          // 32 rows/block, 16B/lane
        int row = blockIdx.x * 32 + grp;
        if (row >= N) return;
        const uint4* x8 = (const uint4*)x;    // row stride = 8 uint4
        int s = row_ptr[row], e = row_ptr[row + 1];
        float a0[8] = {0,0,0,0,0,0,0,0};
        float a1[8] = {0,0,0,0,0,0,0,0};
        float a2[8] = {0,0,0,0,0,0,0,0};
        float a3[8] = {0,0,0,0,0,0,0,0};
        for (int j = s; j < e; j += 8) {
            #pragma unroll
            for (int k = 0; k < 8; k++) {
                int jj = j + k;
                bool ok = jj < e;
                int c = col[ok ? jj : (e - 1)];     // clamped: same line, cache-hit
                uint4 v = x8[(size_t)c * 8 + f];
                if (!ok) { v.x = 0; v.y = 0; v.z = 0; v.w = 0; }
                if ((k & 3) == 0) addbf8(a0, v);
                else if ((k & 3) == 1) addbf8(a1, v);
                else if ((k & 3) == 2) addbf8(a2, v);
                else addbf8(a3, v);
            }
        }
        float rdeg = (e > s) ? (1.0f / (float)(e - s)) : 0.0f;
        uint4 o;
        float s0, s1;
        s0 = (a0[0]+a1[0]+a2[0]+a3[0]) * rdeg; s1 = (a0[1]+a1[1]+a2[1]+a3[1]) * rdeg;
        o.x = (unsigned)f2bf(s0) | ((unsigned)f2bf(s1) << 16);
        s0 = (a0[2]+a1[2]+a2[2]+a3[2]) * rdeg; s1 = (a0[3]+a1[3]+a2[3]+a3[3]) * rdeg;
        o.y = (unsigned)f2bf(s0) | ((unsigned)f2bf(s1) << 16);
        s0 = (a0[4]+a1[4]+a2[4]+a3[4]) * rdeg; s1 = (a0[5]+a1[5]+a2[5]+a3[5]) * rdeg;
        o.z = (unsigned)f2bf(s0) | ((unsigned)f2bf(s1) << 16);
        s0 = (a0[6]+a1[6]+a2[6]+a3[6]) * rdeg; s1 = (a0[7]+a1[7]+a2[7]+a3[7]) * rdeg;
        o.w = (unsigned)f2bf(s0) | ((unsigned)f2bf(s1) << 16);
        ((uint4*)y)[(size_t)row * 8 + f] = o;
    } else {
        if (mode == 0) return;
        int grp = t >> 4, f4 = t & 15;
        int b = (blockIdx.x - nBlkMain) * 16 + grp;
        if (b >= 2 * B) return;
        const ushort4* x4 = (const ushort4*)x;
        int row = (b < B) ? users[b] : (nU + items[b - B]);
        int deg = row_ptr[row + 1] - row_ptr[row];
        float f = sqrtf((float)deg);
        ushort4 v = x4[(size_t)row * 16 + f4];
        float4 c = ((const float4*)acc)[(size_t)b * 16 + f4];
        c.x += f * bf2f(v.x); c.y += f * bf2f(v.y);
        c.z += f * bf2f(v.z); c.w += f * bf2f(v.w);
        ((float4*)acc)[(size_t)b * 16 + f4] = c;
    }
}

// ---------------- layer-3 + layer-4 terms at batch rows only ---------------------
__global__ void k_tail34(const int* __restrict__ row_ptr, const int* __restrict__ col,
                         const unsigned short* __restrict__ z3,
                         const int* __restrict__ users, const int* __restrict__ items,
                         int B, int nU, float* __restrict__ acc) {
    int t = threadIdx.x, grp = t >> 3, f = t & 7;
    int b = blockIdx.x * 32 + grp;
    if (b >= 2 * B) return;
    int row = (b < B) ? users[b] : (nU + items[b - B]);
    int s = row_ptr[row], e = row_ptr[row + 1];
    const uint4* x8 = (const uint4*)z3;
    float4 cA = ((const float4*)acc)[(size_t)b * 16 + 2 * f];
    float4 cB = ((const float4*)acc)[(size_t)b * 16 + 2 * f + 1];
    if (e > s) {
        float fq = sqrtf((float)(e - s));
        float a0[8] = {0,0,0,0,0,0,0,0};
        float a1[8] = {0,0,0,0,0,0,0,0};
        int j = s;
        for (; j + 1 < e; j += 2) {
            uint4 v0 = x8[(size_t)col[j] * 8 + f];
            uint4 v1 = x8[(size_t)col[j + 1] * 8 + f];
            addbf8(a0, v0); addbf8(a1, v1);
        }
        if (j < e) {
            uint4 v0 = x8[(size_t)col[j] * 8 + f];
            addbf8(a0, v0);
        }
        uint4 vs = x8[(size_t)row * 8 + f];
        float self[8] = {0,0,0,0,0,0,0,0};
        addbf8(self, vs);
        float scale = fq / (float)(e - s);
        cA.x += fq * self[0] + scale * (a0[0] + a1[0]);
        cA.y += fq * self[1] + scale * (a0[1] + a1[1]);
        cA.z += fq * self[2] + scale * (a0[2] + a1[2]);
        cA.w += fq * self[3] + scale * (a0[3] + a1[3]);
        cB.x += fq * self[4] + scale * (a0[4] + a1[4]);
        cB.y += fq * self[5] + scale * (a0[5] + a1[5]);
        cB.z += fq * self[6] + scale * (a0[6] + a1[6]);
        cB.w += fq * self[7] + scale * (a0[7] + a1[7]);
    }
    ((float4*)acc)[(size_t)b * 16 + 2 * f]     = cA;
    ((float4*)acc)[(size_t)b * 16 + 2 * f + 1] = cB;
}

// ---------------- final: gamma[b] = dot(acc_u[b], acc_i[b]) / 25 -----------------
__global__ void k_dot(const float* __restrict__ acc, int B, float* __restrict__ out) {
    int b = blockIdx.x * (blockDim.x >> 6) + (threadIdx.x >> 6);
    int lane = threadIdx.x & 63;
    if (b >= B) return;
    float p = acc[(size_t)b * 64 + lane] * acc[(size_t)(b + B) * 64 + lane];
    #pragma unroll
    for (int o = 32; o > 0; o >>= 1) p += __shfl_down(p, o, WAVE);
    if (lane == 0) out[b] = p * (1.0f / 25.0f);
}

extern "C" void kernel_launch(void* const* d_in, const int* in_sizes, int n_in,
                              void* d_out, int out_size, void* d_ws, size_t ws_size,
                              hipStream_t stream) {
    const int*   users = (const int*)d_in[0];
    const int*   items = (const int*)d_in[1];
    const int*   eu    = (const int*)d_in[2];
    const int*   ei    = (const int*)d_in[3];
    const float* ue    = (const float*)d_in[4];
    const float* ie    = (const float*)d_in[5];
    float* out = (float*)d_out;

    const int D  = 64;
    int B  = in_sizes[0];
    int nE = in_sizes[2];
    int nU = in_sizes[4] / D;
    const int nI = in_sizes[5] / D;
    int N  = nU + nI;
    int nBkt = (N + BROWS - 1) / BROWS;         // 586 (must be <= 1024)
    int total = 2 * nE;
    int nChunk = (nE + EPC - 1) / EPC;          // 586

    // ---- carve workspace (256B-aligned chunks) ----
    char* p = (char*)d_ws;
    auto alloc = [&](size_t bytes) -> void* {
        void* r = (void*)p;
        p += (bytes + 255) & ~(size_t)255;
        return r;
    };
    int*   cntBB   = (int*)  alloc((size_t)nChunk * nBkt * 4);   // 1.37 MB
    int*   baseBB  = (int*)  alloc((size_t)nBkt * nChunk * 4);   // 1.37 MB
    int*   bktTot  = (int*)  alloc((size_t)nBkt * 4);
    int*   bktBase = (int*)  alloc((size_t)(nBkt + 1) * 4);
    int*   bins    = (int*)  alloc((size_t)total * 4);           // 4.8 MB
    int*   col     = (int*)  alloc((size_t)total * 4);           // 4.8 MB
    int*   row_ptr = (int*)  alloc((size_t)(N + 1) * 4);
    unsigned short* za = (unsigned short*)alloc((size_t)N * D * 2);  // 19.2 MB
    unsigned short* zb = (unsigned short*)alloc((size_t)N * D * 2);  // 19.2 MB
    float* acc     = (float*)alloc((size_t)2 * B * D * 4);

    // ---- fused cooperative build (hist/scan/scan/bin/csr+z0, acc=x0 overlap) ----
    {
        const int* eu_ = eu; const int* ei_ = ei;
        const float* ue_ = ue; const float* ie_ = ie;
        const int* users_ = users; const int* items_ = items;
        void* args[] = {
            (void*)&eu_, (void*)&ei_, (void*)&nE, (void*)&nU, (void*)&nBkt,
            (void*)&nChunk, (void*)&cntBB, (void*)&baseBB, (void*)&bktTot,
            (void*)&bktBase, (void*)&bins, (void*)&row_ptr, (void*)&col,
            (void*)&za, (void*)&ue_, (void*)&ie_, (void*)&users_, (void*)&items_,
            (void*)&B, (void*)&acc, (void*)&N, (void*)&total };
        hipLaunchCooperativeKernel((void*)k_build, dim3(GRID_BUILD), dim3(256),
                                   args, 0, stream);
    }

    // ---- 3 full propagation layers (z1,z2,z3); tails add x1,x2 -------------------
    const int nBlkMain = (N + 31) / 32;
    const int nBlkTail = (2 * B + 15) / 16;
    unsigned short* zin = za;
    unsigned short* zout = zb;
    for (int l = 0; l < 3; l++) {
        int mode = (l == 0) ? 0 : 1;
        int nBlk = nBlkMain + ((l == 0) ? 0 : nBlkTail);  // l=0: no tail (acc=x0 in build)
        k_spmm<<<nBlk, 256, 0, stream>>>(row_ptr, col, zin, zout, N, nBlkMain,
                                         users, items, B, nU, acc, mode);
        unsigned short* t = zin; zin = zout; zout = t;
    }

    // ---- layer-3 + layer-4 terms at batch rows only, then dot ----
    const int nBlkT34 = (2 * B + 31) / 32;
    k_tail34<<<nBlkT34, 256, 0, stream>>>(row_ptr, col, zin, users, items, B, nU, acc);
    k_dot<<<(B + 3) / 4, 256, 0, stream>>>(acc, B, out);
}

// Round 18
// 208.441 us; speedup vs baseline: 2.2359x; 2.2359x over previous
//
#include <hip/hip_runtime.h>

#define WAVE 64
#define BROWS 256        // rows per bucket (bucket = node >> 8)
#define NBKT_MAX 1024
#define CMAX 4           // max per-thread chunk in k_scanBkt (nJ <= 256*CMAX)
#define SRCMASK 0x3FFFF  // 18-bit src field in packed bins entry
#define EPB 2048         // edges per build block (256 threads x 8)
#define ENTCAP 4096      // LDS entry cache per bucket in k_csrz

// z stored BF16 row-major z[node][64] (128 B). Accumulation fp32 throughout.

__device__ __forceinline__ unsigned short f2bf(float f) {
    unsigned u = __float_as_uint(f);
    u += 0x7FFF + ((u >> 16) & 1);   // round-to-nearest-even
    return (unsigned short)(u >> 16);
}
__device__ __forceinline__ float bf2f(unsigned short v) {
    return __uint_as_float((unsigned)v << 16);
}
// unpack uint4 (8 bf16) and add into a[8]
__device__ __forceinline__ void addbf8(float* a, uint4 v) {
    a[0] += __uint_as_float(v.x << 16);
    a[1] += __uint_as_float(v.x & 0xFFFF0000u);
    a[2] += __uint_as_float(v.y << 16);
    a[3] += __uint_as_float(v.y & 0xFFFF0000u);
    a[4] += __uint_as_float(v.z << 16);
    a[5] += __uint_as_float(v.z & 0xFFFF0000u);
    a[6] += __uint_as_float(v.w << 16);
    a[7] += __uint_as_float(v.w & 0xFFFF0000u);
}

// ---------------- phase 1: per-block bucket histogram (2048 edges/block) --------
__global__ void k_hist(const int* __restrict__ eu, const int* __restrict__ ei,
                       int nE, int nU, int nBkt, int nJg, int* __restrict__ cntBB) {
    __shared__ int h4[4 * NBKT_MAX];
    for (int i = threadIdx.x; i < 4 * nBkt; i += 256) h4[i] = 0;
    __syncthreads();
    int* hw = h4 + (threadIdx.x >> 6) * nBkt;    // per-wave sub-histogram
    const int4* eu4 = (const int4*)eu;
    const int4* ei4 = (const int4*)ei;
    for (int pass = 0; pass < 2; pass++) {
        int i4 = blockIdx.x * 512 + pass * 256 + threadIdx.x;
        int e0 = i4 * 4;
        if (e0 + 3 < nE) {
            int4 u = eu4[i4];
            int4 v = ei4[i4];
            atomicAdd(&hw[u.x >> 8], 1); atomicAdd(&hw[(nU + v.x) >> 8], 1);
            atomicAdd(&hw[u.y >> 8], 1); atomicAdd(&hw[(nU + v.y) >> 8], 1);
            atomicAdd(&hw[u.z >> 8], 1); atomicAdd(&hw[(nU + v.z) >> 8], 1);
            atomicAdd(&hw[u.w >> 8], 1); atomicAdd(&hw[(nU + v.w) >> 8], 1);
        } else if (e0 < nE) {
            for (int e = e0; e < nE; e++) {
                atomicAdd(&hw[eu[e] >> 8], 1);
                atomicAdd(&hw[(nU + ei[e]) >> 8], 1);
            }
        }
    }
    __syncthreads();
    int j = (blockIdx.x & 7) * nJg + (blockIdx.x >> 3);   // XCD-affine block order
    int* dst = cntBB + (size_t)j * nBkt;
    for (int i = threadIdx.x; i < nBkt; i += 256)
        dst[i] = h4[i] + h4[nBkt + i] + h4[2 * nBkt + i] + h4[3 * nBkt + i];
}

// ---------------- phase 2a: per-bucket scan over blocks -> fragment bases --------
__global__ void k_scanBkt(const int* __restrict__ cntBB, int* __restrict__ baseBB,
                          int* __restrict__ bktTot, int nBkt, int nJ) {
    __shared__ int s[256];
    int b = blockIdx.x, t = threadIdx.x;
    int C = (nJ + 255) / 256;
    int vals[CMAX];
    int sum = 0;
    for (int k = 0; k < CMAX; k++) {
        if (k >= C) break;
        int j = t * C + k;
        int v = (j < nJ) ? cntBB[(size_t)j * nBkt + b] : 0;
        vals[k] = v; sum += v;
    }
    s[t] = sum;
    __syncthreads();
    for (int o = 1; o < 256; o <<= 1) {
        int x = (t >= o) ? s[t - o] : 0;
        __syncthreads();
        s[t] += x;
        __syncthreads();
    }
    int run = s[t] - sum;  // exclusive
    for (int k = 0; k < CMAX; k++) {
        if (k >= C) break;
        int j = t * C + k;
        if (j < nJ) { baseBB[(size_t)b * nJ + j] = run; run += vals[k]; }
    }
    if (t == 0) bktTot[b] = s[255];
}

// ---------------- phase 2b: scan bucket totals -> bktBase, row_ptr[N] ------------
__global__ void k_scanTot(const int* __restrict__ bktTot, int* __restrict__ bktBase,
                          int* __restrict__ row_ptr, int nBkt, int N, int total) {
    __shared__ int s[1024];
    int t = threadIdx.x;
    int v = (t < nBkt) ? bktTot[t] : 0;
    s[t] = v;
    __syncthreads();
    for (int o = 1; o < 1024; o <<= 1) {
        int x = (t >= o) ? s[t - o] : 0;
        __syncthreads();
        s[t] += x;
        __syncthreads();
    }
    if (t < nBkt) bktBase[t] = s[t] - v;
    if (t == 0) { bktBase[nBkt] = total; row_ptr[N] = total; }
}

// ---------------- phase 3: bin entries, LDS-sorted by bucket, coalesced out ------
// entry = ((dst & 255) << 18) | src.  Full blocks stage 4096 entries sorted by
// bucket in LDS, then write out in staged order: consecutive lanes hit
// consecutive global addresses within each bucket run. Tail block scattered.
__global__ void k_bin(const int* __restrict__ eu, const int* __restrict__ ei,
                      int nE, int nU, int nBkt, int nJ, int nJg,
                      const int* __restrict__ baseBB, const int* __restrict__ bktBase,
                      int* __restrict__ bins) {
    __shared__ int ent[2 * EPB];               // 16 KB staged entries
    __shared__ unsigned short ebkt[2 * EPB];   // 8 KB staged bucket ids
    __shared__ int h2[2 * NBKT_MAX];           // two sub-histograms
    __shared__ int lcur[NBKT_MAX];             // local cursor (starts at local base)
    __shared__ int dlt[NBKT_MAX];              // global dest - staged pos
    __shared__ int sp[256];
    int t = threadIdx.x;
    int j = (blockIdx.x & 7) * nJg + (blockIdx.x >> 3);
    const bool fullBlk = ((size_t)(blockIdx.x + 1) * EPB <= (size_t)nE);

    if (!fullBlk) {
        // tail block: old scattered-store path (<= 2048 edges, negligible)
        for (int i = t; i < nBkt; i += 256)
            lcur[i] = bktBase[i] + baseBB[(size_t)i * nJ + j];
        __syncthreads();
        for (int e = blockIdx.x * EPB + t; e < nE; e += 256) {
            int u = eu[e];
            int v = nU + ei[e];
            int p1 = atomicAdd(&lcur[u >> 8], 1);
            int p2 = atomicAdd(&lcur[v >> 8], 1);
            bins[p1] = ((u & 255) << 18) | v;
            bins[p2] = ((v & 255) << 18) | u;
        }
        return;
    }

    for (int i = t; i < nBkt; i += 256) { h2[i] = 0; h2[NBKT_MAX + i] = 0; }
    __syncthreads();
    // load 8 edges -> 16 (bucket, entry) pairs in registers; histogram
    int myb[16], mye[16];
    int* hs = h2 + (t >> 7) * NBKT_MAX;        // waves 0-1 / 2-3 sub-hists
    {
        const int4* eu4 = (const int4*)eu;
        const int4* ei4 = (const int4*)ei;
        #pragma unroll
        for (int pass = 0; pass < 2; pass++) {
            int i4 = blockIdx.x * 512 + pass * 256 + t;
            int4 uu = eu4[i4];
            int4 vv = ei4[i4];
            #pragma unroll
            for (int k = 0; k < 4; k++) {
                int u = (k == 0) ? uu.x : (k == 1) ? uu.y : (k == 2) ? uu.z : uu.w;
                int i2 = (k == 0) ? vv.x : (k == 1) ? vv.y : (k == 2) ? vv.z : vv.w;
                int v = nU + i2;
                int idx = pass * 8 + k * 2;
                myb[idx]     = u >> 8; mye[idx]     = ((u & 255) << 18) | v;
                myb[idx + 1] = v >> 8; mye[idx + 1] = ((v & 255) << 18) | u;
            }
        }
    }
    #pragma unroll
    for (int k = 0; k < 16; k++) atomicAdd(&hs[myb[k]], 1);
    __syncthreads();
    // block scan over buckets -> local bases + global deltas
    int C = (nBkt + 255) / 256;                // <= 4
    int vals[4];
    int sum = 0;
    for (int k = 0; k < 4; k++) {
        if (k >= C) break;
        int b = t * C + k;
        int v = (b < nBkt) ? (h2[b] + h2[NBKT_MAX + b]) : 0;
        vals[k] = v; sum += v;
    }
    sp[t] = sum;
    __syncthreads();
    for (int o = 1; o < 256; o <<= 1) {
        int x = (t >= o) ? sp[t - o] : 0;
        __syncthreads();
        sp[t] += x;
        __syncthreads();
    }
    int run = sp[t] - sum;                     // exclusive
    for (int k = 0; k < 4; k++) {
        if (k >= C) break;
        int b = t * C + k;
        if (b < nBkt) {
            lcur[b] = run;
            int g = bktBase[b] + baseBB[(size_t)b * nJ + j];
            dlt[b] = g - run;
            run += vals[k];
        }
    }
    __syncthreads();
    int n4 = sp[255];                          // total entries (== 4096)
    // placement into LDS staging (sorted by bucket)
    #pragma unroll
    for (int k = 0; k < 16; k++) {
        int p = atomicAdd(&lcur[myb[k]], 1);
        ent[p] = mye[k];
        ebkt[p] = (unsigned short)myb[k];
    }
    __syncthreads();
    // write-out: consecutive staged positions -> consecutive global addresses
    for (int i = t; i < n4; i += 256)
        bins[dlt[ebkt[i]] + i] = ent[i];
}

// ---------------- phase 4: CSR finalize, LDS entry cache, fused z0 ---------------
__global__ void k_csrz(const int* __restrict__ bins, const int* __restrict__ bktBase,
                       int N, int nU,
                       const float* __restrict__ ue, const float* __restrict__ ie,
                       int* __restrict__ row_ptr, int* __restrict__ col,
                       unsigned short* __restrict__ z0) {
    __shared__ int ent[ENTCAP];
    __shared__ int h4[4 * BROWS];
    __shared__ int sc[BROWS];
    __shared__ int cur4[4 * BROWS];
    __shared__ float sInv[BROWS];
    int b = blockIdx.x, t = threadIdx.x, w = t >> 6;
    int base = bktBase[b];
    int n = bktBase[b + 1] - base;
    h4[t] = 0; h4[256 + t] = 0; h4[512 + t] = 0; h4[768 + t] = 0;
    __syncthreads();
    int* hw = h4 + w * BROWS;
    for (int i = t; i < n; i += 256) {
        int p = bins[base + i];
        if (i < ENTCAP) ent[i] = p;
        atomicAdd(&hw[p >> 18], 1);
    }
    __syncthreads();
    int v = h4[t] + h4[256 + t] + h4[512 + t] + h4[768 + t];
    sc[t] = v;
    __syncthreads();
    for (int o = 1; o < 256; o <<= 1) {
        int x = (t >= o) ? sc[t - o] : 0;
        __syncthreads();
        sc[t] += x;
        __syncthreads();
    }
    int excl = sc[t] - v;
    int row = b * BROWS + t;
    if (row < N) row_ptr[row] = base + excl;
    sInv[t] = (v > 0) ? (1.0f / sqrtf((float)v)) : 0.0f;
    // per-wave cursor bases (wave w places its own subset, no cross-wave atomics)
    cur4[t]       = excl;
    cur4[256 + t] = excl + h4[t];
    cur4[512 + t] = excl + h4[t] + h4[256 + t];
    cur4[768 + t] = excl + h4[t] + h4[256 + t] + h4[512 + t];
    __syncthreads();
    // fused z0 = inv .* x0 (bf16 RTNE), 16 rows per pass, coalesced
    int rf = t & 15, rg = t >> 4;
    for (int pass = 0; pass < 16; pass++) {
        int r = pass * 16 + rg;
        int rr = b * BROWS + r;
        if (rr < N) {
            const float4* src = (rr < nU)
                ? ((const float4*)ue) + (size_t)rr * 16
                : ((const float4*)ie) + (size_t)(rr - nU) * 16;
            float4 val = src[rf];
            float scl = sInv[r];
            ushort4 o;
            o.x = f2bf(val.x * scl);
            o.y = f2bf(val.y * scl);
            o.z = f2bf(val.z * scl);
            o.w = f2bf(val.w * scl);
            ((ushort4*)z0)[(size_t)rr * 16 + rf] = o;
        }
    }
    // placement with per-wave cursors (same i -> thread mapping as histogram)
    int* cw = cur4 + w * BROWS;
    for (int i = t; i < n; i += 256) {
        int p = (i < ENTCAP) ? ent[i] : bins[base + i];
        int pos = base + atomicAdd(&cw[p >> 18], 1);
        col[pos] = p & SRCMASK;
    }
}

// ---------------- SPMM: masked 8-wide gather (divergence-flattened) --------------
__global__ void k_spmm(const int* __restrict__ row_ptr, const int* __restrict__ col,
                       const unsigned short* __restrict__ x,
                       unsigned short* __restrict__ y, int N, int nBlkMain,
                       const int* __restrict__ users, const int* __restrict__ items,
                       int B, int nU,
                       const float* __restrict__ ue, const float* __restrict__ ie,
                       float* __restrict__ acc, int mode) {
    int t = threadIdx.x;
    if ((int)blockIdx.x < nBlkMain) {
        int grp = t >> 3, f = t & 7;          // 32 rows/block, 16B/lane
        int row = blockIdx.x * 32 + grp;
        if (row >= N) return;
        const uint4* x8 = (const uint4*)x;    // row stride = 8 uint4
        int s = row_ptr[row], e = row_ptr[row + 1];
        float a0[8] = {0,0,0,0,0,0,0,0};
        float a1[8] = {0,0,0,0,0,0,0,0};
        float a2[8] = {0,0,0,0,0,0,0,0};
        float a3[8] = {0,0,0,0,0,0,0,0};
        for (int j = s; j < e; j += 8) {
            #pragma unroll
            for (int k = 0; k < 8; k++) {
                int jj = j + k;
                bool ok = jj < e;
                int c = col[ok ? jj : (e - 1)];     // clamped: same line, cache-hit
                uint4 v = x8[(size_t)c * 8 + f];
                if (!ok) { v.x = 0; v.y = 0; v.z = 0; v.w = 0; }
                if ((k & 3) == 0) addbf8(a0, v);
                else if ((k & 3) == 1) addbf8(a1, v);
                else if ((k & 3) == 2) addbf8(a2, v);
                else addbf8(a3, v);
            }
        }
        float rdeg = (e > s) ? (1.0f / (float)(e - s)) : 0.0f;
        uint4 o;
        float s0, s1;
        s0 = (a0[0]+a1[0]+a2[0]+a3[0]) * rdeg; s1 = (a0[1]+a1[1]+a2[1]+a3[1]) * rdeg;
        o.x = (unsigned)f2bf(s0) | ((unsigned)f2bf(s1) << 16);
        s0 = (a0[2]+a1[2]+a2[2]+a3[2]) * rdeg; s1 = (a0[3]+a1[3]+a2[3]+a3[3]) * rdeg;
        o.y = (unsigned)f2bf(s0) | ((unsigned)f2bf(s1) << 16);
        s0 = (a0[4]+a1[4]+a2[4]+a3[4]) * rdeg; s1 = (a0[5]+a1[5]+a2[5]+a3[5]) * rdeg;
        o.z = (unsigned)f2bf(s0) | ((unsigned)f2bf(s1) << 16);
        s0 = (a0[6]+a1[6]+a2[6]+a3[6]) * rdeg; s1 = (a0[7]+a1[7]+a2[7]+a3[7]) * rdeg;
        o.w = (unsigned)f2bf(s0) | ((unsigned)f2bf(s1) << 16);
        ((uint4*)y)[(size_t)row * 8 + f] = o;
    } else {
        int grp = t >> 4, f4 = t & 15;
        int b = (blockIdx.x - nBlkMain) * 16 + grp;
        if (b >= 2 * B) return;
        const ushort4* x4 = (const ushort4*)x;
        float4 c;
        if (mode == 0) {
            const float4* x0 = (b < B)
                ? ((const float4*)ue) + (size_t)users[b] * 16
                : ((const float4*)ie) + (size_t)items[b - B] * 16;
            c = x0[f4];
        } else {
            int row = (b < B) ? users[b] : (nU + items[b - B]);
            int deg = row_ptr[row + 1] - row_ptr[row];
            float f = sqrtf((float)deg);
            ushort4 v = x4[(size_t)row * 16 + f4];
            c = ((const float4*)acc)[(size_t)b * 16 + f4];
            c.x += f * bf2f(v.x); c.y += f * bf2f(v.y);
            c.z += f * bf2f(v.z); c.w += f * bf2f(v.w);
        }
        ((float4*)acc)[(size_t)b * 16 + f4] = c;
    }
}

// ---------------- layer-3 + layer-4 terms at batch rows only ---------------------
// acc[b] += sqrt(deg)*z3[row] + sqrt(deg)/deg * sum_{c in N(row)} z3[c]
__global__ void k_tail34(const int* __restrict__ row_ptr, const int* __restrict__ col,
                         const unsigned short* __restrict__ z3,
                         const int* __restrict__ users, const int* __restrict__ items,
                         int B, int nU, float* __restrict__ acc) {
    int t = threadIdx.x, grp = t >> 3, f = t & 7;
    int b = blockIdx.x * 32 + grp;
    if (b >= 2 * B) return;
    int row = (b < B) ? users[b] : (nU + items[b - B]);
    int s = row_ptr[row], e = row_ptr[row + 1];
    const uint4* x8 = (const uint4*)z3;
    float4 cA = ((const float4*)acc)[(size_t)b * 16 + 2 * f];
    float4 cB = ((const float4*)acc)[(size_t)b * 16 + 2 * f + 1];
    if (e > s) {
        float fq = sqrtf((float)(e - s));
        float a0[8] = {0,0,0,0,0,0,0,0};
        float a1[8] = {0,0,0,0,0,0,0,0};
        int j = s;
        for (; j + 1 < e; j += 2) {
            uint4 v0 = x8[(size_t)col[j] * 8 + f];
            uint4 v1 = x8[(size_t)col[j + 1] * 8 + f];
            addbf8(a0, v0); addbf8(a1, v1);
        }
        if (j < e) {
            uint4 v0 = x8[(size_t)col[j] * 8 + f];
            addbf8(a0, v0);
        }
        uint4 vs = x8[(size_t)row * 8 + f];
        float self[8] = {0,0,0,0,0,0,0,0};
        addbf8(self, vs);
        float scale = fq / (float)(e - s);
        cA.x += fq * self[0] + scale * (a0[0] + a1[0]);
        cA.y += fq * self[1] + scale * (a0[1] + a1[1]);
        cA.z += fq * self[2] + scale * (a0[2] + a1[2]);
        cA.w += fq * self[3] + scale * (a0[3] + a1[3]);
        cB.x += fq * self[4] + scale * (a0[4] + a1[4]);
        cB.y += fq * self[5] + scale * (a0[5] + a1[5]);
        cB.z += fq * self[6] + scale * (a0[6] + a1[6]);
        cB.w += fq * self[7] + scale * (a0[7] + a1[7]);
    }
    ((float4*)acc)[(size_t)b * 16 + 2 * f]     = cA;
    ((float4*)acc)[(size_t)b * 16 + 2 * f + 1] = cB;
}

// ---------------- final: gamma[b] = dot(acc_u[b], acc_i[b]) / 25 -----------------
__global__ void k_dot(const float* __restrict__ acc, int B, float* __restrict__ out) {
    int b = blockIdx.x * (blockDim.x >> 6) + (threadIdx.x >> 6);
    int lane = threadIdx.x & 63;
    if (b >= B) return;
    float p = acc[(size_t)b * 64 + lane] * acc[(size_t)(b + B) * 64 + lane];
    #pragma unroll
    for (int o = 32; o > 0; o >>= 1) p += __shfl_down(p, o, WAVE);
    if (lane == 0) out[b] = p * (1.0f / 25.0f);
}

extern "C" void kernel_launch(void* const* d_in, const int* in_sizes, int n_in,
                              void* d_out, int out_size, void* d_ws, size_t ws_size,
                              hipStream_t stream) {
    const int*   users = (const int*)d_in[0];
    const int*   items = (const int*)d_in[1];
    const int*   eu    = (const int*)d_in[2];
    const int*   ei    = (const int*)d_in[3];
    const float* ue    = (const float*)d_in[4];
    const float* ie    = (const float*)d_in[5];
    float* out = (float*)d_out;

    const int D  = 64;
    const int B  = in_sizes[0];
    const int nE = in_sizes[2];
    const int nU = in_sizes[4] / D;
    const int nI = in_sizes[5] / D;
    const int N  = nU + nI;
    const int nBkt = (N + BROWS - 1) / BROWS;   // 586 (<= NBKT_MAX required)
    const int total = 2 * nE;

    const int nBlkB = (nE + EPB - 1) / EPB;     // 293 build blocks w/ edges
    const int nJg   = (nBlkB + 7) / 8;          // 38
    const int nJ    = 8 * nJg;                  // 304 (empty blocks write zero rows)

    // ---- carve workspace (256B-aligned chunks) ----
    char* p = (char*)d_ws;
    auto alloc = [&](size_t bytes) -> void* {
        void* r = (void*)p;
        p += (bytes + 255) & ~(size_t)255;
        return r;
    };
    int*   cntBB   = (int*)  alloc((size_t)nJ * nBkt * 4);     // 0.7 MB
    int*   baseBB  = (int*)  alloc((size_t)nBkt * nJ * 4);     // 0.7 MB
    int*   bktTot  = (int*)  alloc((size_t)nBkt * 4);
    int*   bktBase = (int*)  alloc((size_t)(nBkt + 1) * 4);
    int*   bins    = (int*)  alloc((size_t)total * 4);         // 4.8 MB packed
    int*   col     = (int*)  alloc((size_t)total * 4);         // 4.8 MB
    int*   row_ptr = (int*)  alloc((size_t)(N + 1) * 4);
    unsigned short* za = (unsigned short*)alloc((size_t)N * D * 2);  // 19.2 MB bf16
    unsigned short* zb = (unsigned short*)alloc((size_t)N * D * 2);  // 19.2 MB bf16
    float* acc     = (float*)alloc((size_t)2 * B * D * 4);

    // ---- build CSR: zero global atomics ----
    k_hist<<<nJ, 256, 0, stream>>>(eu, ei, nE, nU, nBkt, nJg, cntBB);
    k_scanBkt<<<nBkt, 256, 0, stream>>>(cntBB, baseBB, bktTot, nBkt, nJ);
    k_scanTot<<<1, 1024, 0, stream>>>(bktTot, bktBase, row_ptr, nBkt, N, total);
    k_bin<<<nJ, 256, 0, stream>>>(eu, ei, nE, nU, nBkt, nJ, nJg, baseBB, bktBase, bins);
    k_csrz<<<nBkt, BROWS, 0, stream>>>(bins, bktBase, N, nU, ue, ie, row_ptr, col, za);

    // ---- 3 full propagation layers (z1,z2,z3), batch-accumulate fused in tail ----
    const int nBlkMain = (N + 31) / 32;
    const int nBlkTail = (2 * B + 15) / 16;
    unsigned short* zin = za;
    unsigned short* zout = zb;
    for (int l = 0; l < 3; l++) {
        k_spmm<<<nBlkMain + nBlkTail, 256, 0, stream>>>(
            row_ptr, col, zin, zout, N, nBlkMain,
            users, items, B, nU, ue, ie, acc, (l == 0) ? 0 : 1);
        unsigned short* t = zin; zin = zout; zout = t;
    }

    // ---- layer-3 + layer-4 terms at batch rows only, then dot ----
    const int nBlkT34 = (2 * B + 31) / 32;
    k_tail34<<<nBlkT34, 256, 0, stream>>>(row_ptr, col, zin, users, items, B, nU, acc);
    k_dot<<<(B + 3) / 4, 256, 0, stream>>>(acc, B, out);
}